// Round 3
// baseline (469.132 us; speedup 1.0000x reference)
//
#include <hip/hip_runtime.h>
#include <hip/hip_bf16.h>

// ---------------------------------------------------------------------------
// GAT link predictor: 2x GATConv + pair MLP, fp32 end-to-end.
// R3: channel-tiled L2-resident aggregation (alpha precompute + 16-channel
//     tile passes, tile = blockIdx&7 -> per-XCD L2 slab), u16 CSR,
//     hierarchical scan.
// ---------------------------------------------------------------------------

#define LRELU_SLOPE 0.2f

// ---- weight pre-transpose (so GEMM W reads are wave-uniform -> s_load) ----
__global__ void __launch_bounds__(256) prep_kernel(
    const float* __restrict__ W1, const float* __restrict__ W2,
    const float* __restrict__ Wm1,
    float* __restrict__ W1T, float* __restrict__ W2T, float* __restrict__ Wm1T)
{
    int i = blockIdx.x * 256 + threadIdx.x;
    if (i < 16384) {                       // W1 [128][128] -> W1T [128][128]
        int k = i >> 7, j = i & 127;
        W1T[j * 128 + k] = W1[i];
    } else if (i < 16384 + 8192) {         // W2 [128][64] -> W2T [64][128]
        int t = i - 16384;
        int k = t >> 6, j = t & 63;
        W2T[j * 128 + k] = W2[t];
    } else if (i < 16384 + 8192 + 4096) {  // Wm1 [128][32] -> Wm1T [32][128]
        int t = i - 24576;
        int k = t >> 5, j = t & 31;
        Wm1T[j * 128 + k] = Wm1[t];
    }
}

// ---- CSR build ----
__global__ void __launch_bounds__(256) hist_kernel(
    const int* __restrict__ dst, int E, int N, int* __restrict__ deg)
{
    int i = blockIdx.x * 256 + threadIdx.x;
    if (i >= E + N) return;
    int d = (i < E) ? dst[i] : (i - E);
    atomicAdd(deg + d, 1);
}

// hierarchical scan: per-1024-block inclusive scan + block totals
__global__ void __launch_bounds__(1024) scan1_kernel(
    const int* __restrict__ deg, int* __restrict__ rowp,
    int* __restrict__ btot, int n)
{
    __shared__ int wsum[16];
    int t = threadIdx.x, lane = t & 63, wid = t >> 6;
    int idx = blockIdx.x * 1024 + t;
    int v = (idx < n) ? deg[idx] : 0;
    #pragma unroll
    for (int off = 1; off < 64; off <<= 1) {
        int y = __shfl_up(v, off);
        if (lane >= off) v += y;
    }
    if (lane == 63) wsum[wid] = v;
    __syncthreads();
    if (wid == 0) {
        int s = (lane < 16) ? wsum[lane] : 0;
        #pragma unroll
        for (int off = 1; off < 16; off <<= 1) {
            int y = __shfl_up(s, off);
            if (lane >= off) s += y;
        }
        if (lane < 16) wsum[lane] = s;
    }
    __syncthreads();
    if (wid > 0) v += wsum[wid - 1];
    if (idx < n) rowp[idx + 1] = v;
    if (t == 1023) btot[blockIdx.x] = v;
    if (idx == 0) rowp[0] = 0;
}

__global__ void __launch_bounds__(64) scan2_kernel(int* __restrict__ btot, int nb)
{
    int lane = threadIdx.x;
    int v = (lane < nb) ? btot[lane] : 0;
    #pragma unroll
    for (int off = 1; off < 64; off <<= 1) {
        int y = __shfl_up(v, off);
        if (lane >= off) v += y;
    }
    if (lane < nb) btot[lane] = v;
}

__global__ void __launch_bounds__(1024) scan3_kernel(
    int* __restrict__ rowp, const int* __restrict__ btot, int n)
{
    if (blockIdx.x == 0) return;
    int idx = blockIdx.x * 1024 + threadIdx.x;
    if (idx < n) rowp[idx + 1] += btot[blockIdx.x - 1];
}

__global__ void __launch_bounds__(256) scatter_kernel(
    const int* __restrict__ src, const int* __restrict__ dst, int E, int N,
    const int* __restrict__ rowptr, int* __restrict__ cursor,
    unsigned short* __restrict__ csrs)
{
    int i = blockIdx.x * 256 + threadIdx.x;
    if (i >= E + N) return;
    int s, d;
    if (i < E) { s = src[i]; d = dst[i]; } else { s = d = i - E; }
    int pos = rowptr[d] + atomicAdd(cursor + d, 1);
    csrs[pos] = (unsigned short)s;
}

// ---- fused GEMM + attention-score epilogue; OUT in tiled [tile][N][16] ----
__global__ void __launch_bounds__(256) gemm_att_kernel(
    const float* __restrict__ X, const float* __restrict__ WT,
    const float* __restrict__ atts, const float* __restrict__ attd,
    float* __restrict__ OUT, float* __restrict__ oas, float* __restrict__ oad,
    int N, int H, int headShift, int tiledX)
{
    __shared__ float xs[64 * 132];
    int tid = threadIdx.x;
    int rowBase = blockIdx.x * 64;
    int colBase = blockIdx.y * 64;
    const float4* X4 = (const float4*)X;
    for (int i = tid; i < 64 * 32; i += 256) {
        int r = i >> 5, k4 = i & 31;
        int gr = rowBase + r;
        float4 v = make_float4(0.f, 0.f, 0.f, 0.f);
        if (gr < N) {
            size_t fi = tiledX ? (((size_t)(k4 >> 2) * N + gr) * 4 + (k4 & 3))
                               : ((size_t)gr * 32 + k4);
            v = X4[fi];
        }
        *(float4*)(xs + r * 132 + k4 * 4) = v;
    }
    __syncthreads();
    int lane = tid & 63;
    int wv = __builtin_amdgcn_readfirstlane(tid >> 6);
    int jb = colBase + wv * 16;
    const float* wbase = WT + (size_t)jb * 128;
    float acc[16];
    #pragma unroll
    for (int i = 0; i < 16; i++) acc[i] = 0.f;
    const float* xr = xs + lane * 132;
    for (int k0 = 0; k0 < 128; k0 += 4) {
        float4 xv = *(const float4*)(xr + k0);
        #pragma unroll
        for (int i = 0; i < 16; i++) {
            const float* wr = wbase + i * 128 + k0;   // uniform -> s_load
            acc[i] = fmaf(xv.x, wr[0], acc[i]);
            acc[i] = fmaf(xv.y, wr[1], acc[i]);
            acc[i] = fmaf(xv.z, wr[2], acc[i]);
            acc[i] = fmaf(xv.w, wr[3], acc[i]);
        }
    }
    int row = rowBase + lane;
    if (row < N) {
        float pas = 0.f, pad_ = 0.f;
        #pragma unroll
        for (int i = 0; i < 16; i++) {
            pas  = fmaf(acc[i], atts[jb + i], pas);
            pad_ = fmaf(acc[i], attd[jb + i], pad_);
        }
        int head = jb >> headShift;
        atomicAdd(oas + (size_t)row * H + head, pas);
        atomicAdd(oad + (size_t)row * H + head, pad_);
        float* op = OUT + ((size_t)(jb >> 4) * N + row) * 16;
        #pragma unroll
        for (int i = 0; i < 16; i += 4)
            *(float4*)(op + i) = make_float4(acc[i], acc[i+1], acc[i+2], acc[i+3]);
    }
}

// ---- layer-1 alpha precompute: w = exp(lrelu(as[s][h]+ad[n][h])), denom ----
// wave per node; lane = (el<<2)|hh covers 16 edges x 4 heads per chunk.
__global__ void __launch_bounds__(256) alpha1_kernel(
    const unsigned short* __restrict__ csr, const int* __restrict__ rowp,
    const float* __restrict__ as1, const float* __restrict__ ad1,
    float* __restrict__ aE, float* __restrict__ dnm, int N, int Etot)
{
    int lane = threadIdx.x & 63;
    int n = __builtin_amdgcn_readfirstlane(blockIdx.x * 4 + (threadIdx.x >> 6));
    if (n >= N) return;
    int rs = rowp[n], re = rowp[n + 1];
    int el = lane >> 2, hh = lane & 3;
    float adv = ad1[n * 4 + hh];
    float srun = 0.f;
    for (int base = rs; base < re; base += 16) {
        int e = base + el;
        float w = 0.f;
        if (e < re) {
            int s = csr[e];
            float sc = as1[s * 4 + hh] + adv;
            sc = sc > 0.f ? sc : LRELU_SLOPE * sc;
            w = __expf(sc);
            aE[(size_t)hh * Etot + e] = w;
        }
        srun += w;
    }
    srun += __shfl_xor(srun, 4);  srun += __shfl_xor(srun, 8);
    srun += __shfl_xor(srun, 16); srun += __shfl_xor(srun, 32);
    if (lane < 4) dnm[n * 4 + lane] = srun;
}

// ---- layer-1 tiled aggregation: tile = blockIdx&7 (16 ch, L2-resident) ----
// lane: c = lane&15 (channel), e4 = lane>>4 (edge slot), 8 edges/iter.
__global__ void __launch_bounds__(256) agg1_kernel(
    const unsigned short* __restrict__ csr, const int* __restrict__ rowp,
    const float* __restrict__ h1t, const float* __restrict__ aE,
    const float* __restrict__ dnm, const float* __restrict__ b1,
    float* __restrict__ x2t, int N, int Etot)
{
    int t = blockIdx.x & 7;
    int lane = threadIdx.x & 63;
    int n = __builtin_amdgcn_readfirstlane((blockIdx.x >> 3) * 4 + (threadIdx.x >> 6));
    if (n >= N) return;
    int rs = rowp[n], re = rowp[n + 1];
    int c = lane & 15, e4 = lane >> 4;
    const float* ht = h1t + (size_t)t * N * 16;
    const float* aEh = aE + (size_t)(t >> 1) * Etot;
    float acc = 0.f;
    for (int base = rs; base < re; base += 8) {
        int e0 = base + e4, e1 = base + 4 + e4;
        float a0 = 0.f, a1 = 0.f; int s0 = 0, s1 = 0;
        if (e0 < re) { s0 = csr[e0]; a0 = aEh[e0]; }
        if (e1 < re) { s1 = csr[e1]; a1 = aEh[e1]; }
        acc = fmaf(a0, ht[(size_t)s0 * 16 + c], acc);
        acc = fmaf(a1, ht[(size_t)s1 * 16 + c], acc);
    }
    acc += __shfl_xor(acc, 16);
    acc += __shfl_xor(acc, 32);
    if (lane < 16) {
        float inv = 1.f / (dnm[n * 4 + (t >> 1)] + 1e-16f);
        float o = acc * inv + b1[t * 16 + lane];
        o = o > 0.f ? o : (__expf(o) - 1.f);   // ELU
        x2t[((size_t)t * N + n) * 16 + lane] = o;
    }
}

// ---- layer-2 alpha precompute (1 head) ----
__global__ void __launch_bounds__(256) alpha2_kernel(
    const unsigned short* __restrict__ csr, const int* __restrict__ rowp,
    const float* __restrict__ as2, const float* __restrict__ ad2,
    float* __restrict__ aE, float* __restrict__ dnm, int N)
{
    int lane = threadIdx.x & 63;
    int n = __builtin_amdgcn_readfirstlane(blockIdx.x * 4 + (threadIdx.x >> 6));
    if (n >= N) return;
    int rs = rowp[n], re = rowp[n + 1];
    float adv = ad2[n];
    float srun = 0.f;
    for (int base = rs; base < re; base += 64) {
        int e = base + lane;
        float w = 0.f;
        if (e < re) {
            int s = csr[e];
            float sc = as2[s] + adv;
            sc = sc > 0.f ? sc : LRELU_SLOPE * sc;
            w = __expf(sc);
            aE[e] = w;
        }
        srun += w;
    }
    #pragma unroll
    for (int m = 1; m < 64; m <<= 1) srun += __shfl_xor(srun, m);
    if (lane == 0) dnm[n] = srun;
}

// ---- layer-2 tiled aggregation: tile = blockIdx&3, writes hf tiled ----
__global__ void __launch_bounds__(256) agg2_kernel(
    const unsigned short* __restrict__ csr, const int* __restrict__ rowp,
    const float* __restrict__ h2t, const float* __restrict__ aE,
    const float* __restrict__ dnm, const float* __restrict__ b2,
    float* __restrict__ hft, int N)
{
    int t = blockIdx.x & 3;
    int lane = threadIdx.x & 63;
    int n = __builtin_amdgcn_readfirstlane((blockIdx.x >> 2) * 4 + (threadIdx.x >> 6));
    if (n >= N) return;
    int rs = rowp[n], re = rowp[n + 1];
    int c = lane & 15, e4 = lane >> 4;
    const float* ht = h2t + (size_t)t * N * 16;
    float acc = 0.f;
    for (int base = rs; base < re; base += 8) {
        int e0 = base + e4, e1 = base + 4 + e4;
        float a0 = 0.f, a1 = 0.f; int s0 = 0, s1 = 0;
        if (e0 < re) { s0 = csr[e0]; a0 = aE[e0]; }
        if (e1 < re) { s1 = csr[e1]; a1 = aE[e1]; }
        acc = fmaf(a0, ht[(size_t)s0 * 16 + c], acc);
        acc = fmaf(a1, ht[(size_t)s1 * 16 + c], acc);
    }
    acc += __shfl_xor(acc, 16);
    acc += __shfl_xor(acc, 32);
    if (lane < 16) {
        float inv = 1.f / (dnm[n] + 1e-16f);
        hft[((size_t)t * N + n) * 16 + lane] = acc * inv + b2[t * 16 + lane];
    }
}

// ---- per-node MLP projections over tiled hf: u|v = hf[n] @ Wm1 halves ----
__global__ void __launch_bounds__(256) node_mlp_kernel(
    const float* __restrict__ hft, const float* __restrict__ Wm1T,
    float* __restrict__ uv, int N)
{
    int lane = threadIdx.x & 63;
    int j = lane & 31, half = lane >> 5;
    const float* wr = Wm1T + j * 128 + half * 64;   // Wm1T[j][half*64 + k]
    float wreg[64];
    #pragma unroll
    for (int q = 0; q < 16; q++) {
        float4 t = ((const float4*)wr)[q];
        wreg[q*4] = t.x; wreg[q*4+1] = t.y; wreg[q*4+2] = t.z; wreg[q*4+3] = t.w;
    }
    const float4* H4 = (const float4*)hft;
    int wgid = __builtin_amdgcn_readfirstlane(blockIdx.x * 4 + (threadIdx.x >> 6));
    int nwaves = gridDim.x * 4;
    for (int n = wgid; n < N; n += nwaves) {
        float acc = 0.f;
        #pragma unroll
        for (int q = 0; q < 16; q++) {
            float4 hv = H4[((size_t)(q >> 2) * N + n) * 4 + (q & 3)];  // uniform
            acc = fmaf(hv.x, wreg[q*4],   acc);
            acc = fmaf(hv.y, wreg[q*4+1], acc);
            acc = fmaf(hv.z, wreg[q*4+2], acc);
            acc = fmaf(hv.w, wreg[q*4+3], acc);
        }
        uv[(size_t)n * 64 + lane] = acc;
    }
}

// ---- pair MLP: 2 lanes per pair (16 hidden units each), shfl-reduce ----
__global__ void __launch_bounds__(256) pair_mlp_kernel(
    const int* __restrict__ ps, const int* __restrict__ pd,
    const float* __restrict__ uv, const float* __restrict__ bm1,
    const float* __restrict__ Wm2, const float* __restrict__ bm2,
    float* __restrict__ out, int P)
{
    int gid = blockIdx.x * 256 + threadIdx.x;
    int p = gid >> 1;
    if (p >= P) return;
    int half = gid & 1;
    int j0 = half * 16;
    int a = ps[p], b = pd[p];
    const float* ua = uv + (size_t)a * 64 + j0;        // u[a][j0:j0+16]
    const float* vb = uv + (size_t)b * 64 + 32 + j0;   // v[b][j0:j0+16]
    float r = 0.f;
    #pragma unroll
    for (int q = 0; q < 4; q++) {
        float4 uu = ((const float4*)ua)[q];
        float4 vv = ((const float4*)vb)[q];
        float4 bb = ((const float4*)(bm1 + j0))[q];
        float4 ww = ((const float4*)(Wm2 + j0))[q];
        float h0 = uu.x + vv.x + bb.x; h0 = h0 > 0.f ? h0 : 0.f; r = fmaf(h0, ww.x, r);
        float h1 = uu.y + vv.y + bb.y; h1 = h1 > 0.f ? h1 : 0.f; r = fmaf(h1, ww.y, r);
        float h2 = uu.z + vv.z + bb.z; h2 = h2 > 0.f ? h2 : 0.f; r = fmaf(h2, ww.z, r);
        float h3 = uu.w + vv.w + bb.w; h3 = h3 > 0.f ? h3 : 0.f; r = fmaf(h3, ww.w, r);
    }
    r += __shfl_xor(r, 1);
    if (half == 0) out[p] = r + bm2[0];
}

extern "C" void kernel_launch(void* const* d_in, const int* in_sizes, int n_in,
                              void* d_out, int out_size, void* d_ws, size_t ws_size,
                              hipStream_t stream)
{
    const float* x    = (const float*)d_in[0];
    const int*   ei   = (const int*)  d_in[1];
    const int*   ep   = (const int*)  d_in[2];
    const float* W1   = (const float*)d_in[3];
    const float* atS1 = (const float*)d_in[4];
    const float* atD1 = (const float*)d_in[5];
    const float* b1   = (const float*)d_in[6];
    const float* W2   = (const float*)d_in[7];
    const float* atS2 = (const float*)d_in[8];
    const float* atD2 = (const float*)d_in[9];
    const float* b2   = (const float*)d_in[10];
    const float* Wm1  = (const float*)d_in[11];
    const float* bm1  = (const float*)d_in[12];
    const float* Wm2  = (const float*)d_in[13];
    const float* bm2  = (const float*)d_in[14];
    float* out = (float*)d_out;

    int N = in_sizes[0] / 128;
    int E = in_sizes[1] / 2;
    int P = in_sizes[2] / 2;
    int Etot = E + N;

    // workspace carve (256B aligned)
    char* w = (char*)d_ws;
    auto alloc = [&](size_t bytes) {
        char* p = w; w += (bytes + 255) & ~(size_t)255; return p;
    };
    float* W1T  = (float*)alloc(16384 * 4);
    float* W2T  = (float*)alloc(8192 * 4);
    float* Wm1T = (float*)alloc(4096 * 4);
    float* h1t  = (float*)alloc((size_t)N * 128 * 4);   // [8][N][16]
    float* x2t  = (float*)alloc((size_t)N * 128 * 4);   // [8][N][16]
    float* h2t  = (float*)alloc((size_t)N * 64 * 4);    // [4][N][16]
    float* as1  = (float*)alloc((size_t)N * 4 * 4);
    float* ad1  = (float*)alloc((size_t)N * 4 * 4);
    float* as2  = (float*)alloc((size_t)N * 4);
    float* ad2  = (float*)alloc((size_t)N * 4);
    float* dnm1 = (float*)alloc((size_t)N * 4 * 4);
    float* dnm2 = (float*)alloc((size_t)N * 4);
    float* aE1  = (float*)alloc((size_t)4 * Etot * 4);  // [4][Etot]
    int*   deg  = (int*)alloc((size_t)N * 4);
    int*   rowp = (int*)alloc((size_t)(N + 1) * 4);
    int*   curs = (int*)alloc((size_t)N * 4);
    int*   btot = (int*)alloc(64 * 4);
    unsigned short* csrs = (unsigned short*)alloc((size_t)Etot * 2);
    float* aE2 = aE1;       // aE1 dead after agg1
    float* hft = x2t;       // x2t dead after gemm2; [4][N][16]
    float* uv  = h1t;       // h1t dead after agg1; [N][64]

    (void)hipMemsetAsync(deg,  0, (size_t)N * 4, stream);
    (void)hipMemsetAsync(curs, 0, (size_t)N * 4, stream);
    (void)hipMemsetAsync(as1,  0, (size_t)N * 16, stream);
    (void)hipMemsetAsync(ad1,  0, (size_t)N * 16, stream);
    (void)hipMemsetAsync(as2,  0, (size_t)N * 4, stream);
    (void)hipMemsetAsync(ad2,  0, (size_t)N * 4, stream);

    prep_kernel<<<112, 256, 0, stream>>>(W1, W2, Wm1, W1T, W2T, Wm1T);

    int EN = E + N;
    hist_kernel<<<(EN + 255) / 256, 256, 0, stream>>>(ei + E, E, N, deg);
    int nb = (N + 1023) / 1024;
    scan1_kernel<<<nb, 1024, 0, stream>>>(deg, rowp, btot, N);
    scan2_kernel<<<1, 64, 0, stream>>>(btot, nb);
    scan3_kernel<<<nb, 1024, 0, stream>>>(rowp, btot, N);
    scatter_kernel<<<(EN + 255) / 256, 256, 0, stream>>>(ei, ei + E, E, N, rowp, curs, csrs);

    dim3 g1((N + 63) / 64, 2);
    gemm_att_kernel<<<g1, 256, 0, stream>>>(x, W1T, atS1, atD1, h1t, as1, ad1,
                                            N, 4, 5, 0);
    alpha1_kernel<<<(N + 3) / 4, 256, 0, stream>>>(csrs, rowp, as1, ad1, aE1,
                                                   dnm1, N, Etot);
    agg1_kernel<<<8 * ((N + 3) / 4), 256, 0, stream>>>(csrs, rowp, h1t, aE1,
                                                       dnm1, b1, x2t, N, Etot);
    dim3 g2((N + 63) / 64, 1);
    gemm_att_kernel<<<g2, 256, 0, stream>>>(x2t, W2T, atS2, atD2, h2t, as2, ad2,
                                            N, 1, 6, 1);
    alpha2_kernel<<<(N + 3) / 4, 256, 0, stream>>>(csrs, rowp, as2, ad2, aE2,
                                                   dnm2, N);
    agg2_kernel<<<4 * ((N + 3) / 4), 256, 0, stream>>>(csrs, rowp, h2t, aE2,
                                                       dnm2, b2, hft, N);

    node_mlp_kernel<<<1024, 256, 0, stream>>>(hft, Wm1T, uv, N);
    pair_mlp_kernel<<<(2 * P + 255) / 256, 256, 0, stream>>>(ep, ep + P, uv, bm1,
                                                             Wm2, bm2, out, P);
}

// Round 4
// 324.646 us; speedup vs baseline: 1.4451x; 1.4451x over previous
//
#include <hip/hip_runtime.h>
#include <hip/hip_bf16.h>

// ---------------------------------------------------------------------------
// GAT link predictor: 2x GATConv + pair MLP, fp32 end-to-end.
// R4: one-pass gather aggregation with deep MLP: scalar-load CSR (u32,
//     uniform index -> s_load_dwordx16), fully unrolled 16-gather fast path
//     (16 independent dwordx2 in flight). Hierarchical scan, factorized MLP,
//     single fused memset.
// ---------------------------------------------------------------------------

#define LRELU_SLOPE 0.2f

// ---- weight pre-transpose (so GEMM W reads are wave-uniform -> s_load) ----
__global__ void __launch_bounds__(256) prep_kernel(
    const float* __restrict__ W1, const float* __restrict__ W2,
    const float* __restrict__ Wm1,
    float* __restrict__ W1T, float* __restrict__ W2T, float* __restrict__ Wm1T)
{
    int i = blockIdx.x * 256 + threadIdx.x;
    if (i < 16384) {                       // W1 [128][128] -> W1T [128][128]
        int k = i >> 7, j = i & 127;
        W1T[j * 128 + k] = W1[i];
    } else if (i < 16384 + 8192) {         // W2 [128][64] -> W2T [64][128]
        int t = i - 16384;
        int k = t >> 6, j = t & 63;
        W2T[j * 128 + k] = W2[t];
    } else if (i < 16384 + 8192 + 4096) {  // Wm1 [128][32] -> Wm1T [32][128]
        int t = i - 24576;
        int k = t >> 5, j = t & 31;
        Wm1T[j * 128 + k] = Wm1[t];
    }
}

// ---- CSR build ----
__global__ void __launch_bounds__(256) hist_kernel(
    const int* __restrict__ dst, int E, int N, int* __restrict__ deg)
{
    int i = blockIdx.x * 256 + threadIdx.x;
    if (i >= E + N) return;
    int d = (i < E) ? dst[i] : (i - E);
    atomicAdd(deg + d, 1);
}

// hierarchical scan: per-1024-block inclusive scan + block totals
__global__ void __launch_bounds__(1024) scan1_kernel(
    const int* __restrict__ deg, int* __restrict__ rowp,
    int* __restrict__ btot, int n)
{
    __shared__ int wsum[16];
    int t = threadIdx.x, lane = t & 63, wid = t >> 6;
    int idx = blockIdx.x * 1024 + t;
    int v = (idx < n) ? deg[idx] : 0;
    #pragma unroll
    for (int off = 1; off < 64; off <<= 1) {
        int y = __shfl_up(v, off);
        if (lane >= off) v += y;
    }
    if (lane == 63) wsum[wid] = v;
    __syncthreads();
    if (wid == 0) {
        int s = (lane < 16) ? wsum[lane] : 0;
        #pragma unroll
        for (int off = 1; off < 16; off <<= 1) {
            int y = __shfl_up(s, off);
            if (lane >= off) s += y;
        }
        if (lane < 16) wsum[lane] = s;
    }
    __syncthreads();
    if (wid > 0) v += wsum[wid - 1];
    if (idx < n) rowp[idx + 1] = v;
    if (t == 1023) btot[blockIdx.x] = v;
    if (idx == 0) rowp[0] = 0;
}

__global__ void __launch_bounds__(64) scan2_kernel(int* __restrict__ btot, int nb)
{
    int lane = threadIdx.x;
    int v = (lane < nb) ? btot[lane] : 0;
    #pragma unroll
    for (int off = 1; off < 64; off <<= 1) {
        int y = __shfl_up(v, off);
        if (lane >= off) v += y;
    }
    if (lane < nb) btot[lane] = v;
}

__global__ void __launch_bounds__(1024) scan3_kernel(
    int* __restrict__ rowp, const int* __restrict__ btot, int n)
{
    if (blockIdx.x == 0) return;
    int idx = blockIdx.x * 1024 + threadIdx.x;
    if (idx < n) rowp[idx + 1] += btot[blockIdx.x - 1];
}

__global__ void __launch_bounds__(256) scatter_kernel(
    const int* __restrict__ src, const int* __restrict__ dst, int E, int N,
    const int* __restrict__ rowptr, int* __restrict__ cursor,
    int* __restrict__ csrs)
{
    int i = blockIdx.x * 256 + threadIdx.x;
    if (i >= E + N) return;
    int s, d;
    if (i < E) { s = src[i]; d = dst[i]; } else { s = d = i - E; }
    int pos = rowptr[d] + atomicAdd(cursor + d, 1);
    csrs[pos] = s;
}

// ---- fused GEMM + attention-score epilogue ----
// Block: 256 threads = 4 waves; 64 rows x 64 cols. lane = row, wave = 16-col
// slice. x tile in LDS (stride 132), W reads wave-uniform -> s_load.
__global__ void __launch_bounds__(256) gemm_att_kernel(
    const float* __restrict__ X, const float* __restrict__ WT,
    const float* __restrict__ atts, const float* __restrict__ attd,
    float* __restrict__ OUT, float* __restrict__ oas, float* __restrict__ oad,
    int N, int ncols, int H, int headShift)
{
    __shared__ float xs[64 * 132];
    int tid = threadIdx.x;
    int rowBase = blockIdx.x * 64;
    int colBase = blockIdx.y * 64;
    for (int i = tid; i < 64 * 32; i += 256) {
        int r = i >> 5, k4 = i & 31;
        int gr = rowBase + r;
        float4 v = (gr < N) ? ((const float4*)(X + (size_t)gr * 128))[k4]
                            : make_float4(0.f, 0.f, 0.f, 0.f);
        *(float4*)(xs + r * 132 + k4 * 4) = v;
    }
    __syncthreads();
    int lane = tid & 63;
    int wv = __builtin_amdgcn_readfirstlane(tid >> 6);
    int jb = colBase + wv * 16;
    const float* wbase = WT + (size_t)jb * 128;
    float acc[16];
    #pragma unroll
    for (int i = 0; i < 16; i++) acc[i] = 0.f;
    const float* xr = xs + lane * 132;
    for (int k0 = 0; k0 < 128; k0 += 4) {
        float4 xv = *(const float4*)(xr + k0);
        #pragma unroll
        for (int i = 0; i < 16; i++) {
            const float* wr = wbase + i * 128 + k0;   // uniform -> s_load
            acc[i] = fmaf(xv.x, wr[0], acc[i]);
            acc[i] = fmaf(xv.y, wr[1], acc[i]);
            acc[i] = fmaf(xv.z, wr[2], acc[i]);
            acc[i] = fmaf(xv.w, wr[3], acc[i]);
        }
    }
    int row = rowBase + lane;
    if (row < N) {
        float pas = 0.f, pad_ = 0.f;
        #pragma unroll
        for (int i = 0; i < 16; i++) {
            pas  = fmaf(acc[i], atts[jb + i], pas);
            pad_ = fmaf(acc[i], attd[jb + i], pad_);
        }
        int head = jb >> headShift;
        atomicAdd(oas + (size_t)row * H + head, pas);
        atomicAdd(oad + (size_t)row * H + head, pad_);
        float* op = OUT + (size_t)row * ncols + jb;
        #pragma unroll
        for (int i = 0; i < 16; i += 4)
            *(float4*)(op + i) = make_float4(acc[i], acc[i+1], acc[i+2], acc[i+3]);
    }
}

// ---- layer-1 edge pass: one wave per node; 16-edge chunks.
// Weights: lane=(el<<2)|hh. Gather: s via uniform s_load, 16 dwordx2 in
// flight in the cnt==16 fast path; lane owns channels {2lane,2lane+1}.
__global__ void __launch_bounds__(256) edge1_kernel(
    const int* __restrict__ csr, const int* __restrict__ rowp,
    const float* __restrict__ h1, const float* __restrict__ as1,
    const float* __restrict__ ad1, const float* __restrict__ b1,
    float* __restrict__ x2, int N)
{
    int lane = threadIdx.x & 63;
    int n = __builtin_amdgcn_readfirstlane(blockIdx.x * 4 + (threadIdx.x >> 6));
    if (n >= N) return;
    int rs = rowp[n], re = rowp[n + 1];
    int hd = lane >> 4;
    int el = lane >> 2, hh = lane & 3;
    int lo2 = lane * 2;
    float adv = ad1[n * 4 + hh];
    float accx = 0.f, accy = 0.f, srun = 0.f;
    for (int base = rs; base < re; base += 16) {
        int cnt = re - base; if (cnt > 16) cnt = 16;
        float wv = 0.f;
        if (el < cnt) {
            int s = csr[base + el];
            float e = as1[s * 4 + hh] + adv;
            e = e > 0.f ? e : LRELU_SLOPE * e;
            wv = __expf(e);
        }
        float t = wv;
        t += __shfl_xor(t, 4);  t += __shfl_xor(t, 8);
        t += __shfl_xor(t, 16); t += __shfl_xor(t, 32);
        srun += t;
        if (cnt == 16) {
            #pragma unroll
            for (int e2 = 0; e2 < 16; ++e2) {
                int s = csr[base + e2];                    // uniform -> s_load
                float av = __shfl(wv, (e2 << 2) | hd);
                float2 v = *(const float2*)(h1 + (size_t)s * 128 + lo2);
                accx = fmaf(av, v.x, accx);
                accy = fmaf(av, v.y, accy);
            }
        } else {
            for (int e2 = 0; e2 < cnt; ++e2) {
                int s = csr[base + e2];
                float av = __shfl(wv, (e2 << 2) | hd);
                float2 v = *(const float2*)(h1 + (size_t)s * 128 + lo2);
                accx = fmaf(av, v.x, accx);
                accy = fmaf(av, v.y, accy);
            }
        }
    }
    float sden = __shfl(srun, hd) + 1e-16f;
    float inv = 1.f / sden;
    float2 bv = *(const float2*)(b1 + lo2);
    float o0 = accx * inv + bv.x;
    float o1 = accy * inv + bv.y;
    o0 = o0 > 0.f ? o0 : (__expf(o0) - 1.f);   // ELU
    o1 = o1 > 0.f ? o1 : (__expf(o1) - 1.f);
    *(float2*)(x2 + (size_t)n * 128 + lo2) = make_float2(o0, o1);
}

// ---- layer-2 edge pass (1 head, 64 channels; lane = channel) ----
__global__ void __launch_bounds__(256) edge2_kernel(
    const int* __restrict__ csr, const int* __restrict__ rowp,
    const float* __restrict__ h2, const float* __restrict__ as2,
    const float* __restrict__ ad2, const float* __restrict__ b2,
    float* __restrict__ hf, int N)
{
    int lane = threadIdx.x & 63;
    int n = __builtin_amdgcn_readfirstlane(blockIdx.x * 4 + (threadIdx.x >> 6));
    if (n >= N) return;
    int rs = rowp[n], re = rowp[n + 1];
    float adv = ad2[n];
    float acc = 0.f, srun = 0.f;
    for (int base = rs; base < re; base += 16) {
        int cnt = re - base; if (cnt > 16) cnt = 16;
        float wv = 0.f;
        if (lane < cnt) {
            int s = csr[base + lane];
            float e = as2[s] + adv;
            e = e > 0.f ? e : LRELU_SLOPE * e;
            wv = __expf(e);
        }
        srun += wv;
        if (cnt == 16) {
            #pragma unroll
            for (int e2 = 0; e2 < 16; ++e2) {
                int s = csr[base + e2];                    // uniform -> s_load
                float av = __shfl(wv, e2);
                acc = fmaf(av, h2[(size_t)s * 64 + lane], acc);
            }
        } else {
            for (int e2 = 0; e2 < cnt; ++e2) {
                int s = csr[base + e2];
                float av = __shfl(wv, e2);
                acc = fmaf(av, h2[(size_t)s * 64 + lane], acc);
            }
        }
    }
    #pragma unroll
    for (int m = 1; m < 64; m <<= 1) srun += __shfl_xor(srun, m);
    float o = acc / (srun + 1e-16f) + b2[lane];
    hf[(size_t)n * 64 + lane] = o;
}

// ---- per-node MLP projections: u[n] = hf[n]@Wm1_top, v[n] = hf[n]@Wm1_bot --
__global__ void __launch_bounds__(256) node_mlp_kernel(
    const float* __restrict__ hf, const float* __restrict__ Wm1T,
    float* __restrict__ uv, int N)
{
    int lane = threadIdx.x & 63;
    int j = lane & 31, half = lane >> 5;
    const float* wr = Wm1T + j * 128 + half * 64;   // Wm1T[j][half*64 + k]
    float wreg[64];
    #pragma unroll
    for (int q = 0; q < 16; q++) {
        float4 t = ((const float4*)wr)[q];
        wreg[q*4] = t.x; wreg[q*4+1] = t.y; wreg[q*4+2] = t.z; wreg[q*4+3] = t.w;
    }
    int wgid = __builtin_amdgcn_readfirstlane(blockIdx.x * 4 + (threadIdx.x >> 6));
    int nwaves = gridDim.x * 4;
    for (int n = wgid; n < N; n += nwaves) {
        const float* hr = hf + (size_t)n * 64;
        float acc = 0.f;
        #pragma unroll
        for (int k = 0; k < 64; k += 4) {
            float4 hv = *(const float4*)(hr + k);   // uniform across wave
            acc = fmaf(hv.x, wreg[k],   acc);
            acc = fmaf(hv.y, wreg[k+1], acc);
            acc = fmaf(hv.z, wreg[k+2], acc);
            acc = fmaf(hv.w, wreg[k+3], acc);
        }
        uv[(size_t)n * 64 + lane] = acc;
    }
}

// ---- pair MLP: 2 lanes per pair (16 hidden units each), shfl-reduce ----
__global__ void __launch_bounds__(256) pair_mlp_kernel(
    const int* __restrict__ ps, const int* __restrict__ pd,
    const float* __restrict__ uv, const float* __restrict__ bm1,
    const float* __restrict__ Wm2, const float* __restrict__ bm2,
    float* __restrict__ out, int P)
{
    int gid = blockIdx.x * 256 + threadIdx.x;
    int p = gid >> 1;
    if (p >= P) return;
    int half = gid & 1;
    int j0 = half * 16;
    int a = ps[p], b = pd[p];
    const float* ua = uv + (size_t)a * 64 + j0;        // u[a][j0:j0+16]
    const float* vb = uv + (size_t)b * 64 + 32 + j0;   // v[b][j0:j0+16]
    float r = 0.f;
    #pragma unroll
    for (int q = 0; q < 4; q++) {
        float4 uu = ((const float4*)ua)[q];
        float4 vv = ((const float4*)vb)[q];
        float4 bb = ((const float4*)(bm1 + j0))[q];
        float4 ww = ((const float4*)(Wm2 + j0))[q];
        float h0 = uu.x + vv.x + bb.x; h0 = h0 > 0.f ? h0 : 0.f; r = fmaf(h0, ww.x, r);
        float h1 = uu.y + vv.y + bb.y; h1 = h1 > 0.f ? h1 : 0.f; r = fmaf(h1, ww.y, r);
        float h2 = uu.z + vv.z + bb.z; h2 = h2 > 0.f ? h2 : 0.f; r = fmaf(h2, ww.z, r);
        float h3 = uu.w + vv.w + bb.w; h3 = h3 > 0.f ? h3 : 0.f; r = fmaf(h3, ww.w, r);
    }
    r += __shfl_xor(r, 1);
    if (half == 0) out[p] = r + bm2[0];
}

extern "C" void kernel_launch(void* const* d_in, const int* in_sizes, int n_in,
                              void* d_out, int out_size, void* d_ws, size_t ws_size,
                              hipStream_t stream)
{
    const float* x    = (const float*)d_in[0];
    const int*   ei   = (const int*)  d_in[1];
    const int*   ep   = (const int*)  d_in[2];
    const float* W1   = (const float*)d_in[3];
    const float* atS1 = (const float*)d_in[4];
    const float* atD1 = (const float*)d_in[5];
    const float* b1   = (const float*)d_in[6];
    const float* W2   = (const float*)d_in[7];
    const float* atS2 = (const float*)d_in[8];
    const float* atD2 = (const float*)d_in[9];
    const float* b2   = (const float*)d_in[10];
    const float* Wm1  = (const float*)d_in[11];
    const float* bm1  = (const float*)d_in[12];
    const float* Wm2  = (const float*)d_in[13];
    const float* bm2  = (const float*)d_in[14];
    float* out = (float*)d_out;

    int N = in_sizes[0] / 128;
    int E = in_sizes[1] / 2;
    int P = in_sizes[2] / 2;
    int Etot = E + N;

    // workspace carve (256B aligned)
    char* w = (char*)d_ws;
    auto alloc = [&](size_t bytes) {
        char* p = w; w += (bytes + 255) & ~(size_t)255; return p;
    };
    float* W1T  = (float*)alloc(16384 * 4);
    float* W2T  = (float*)alloc(8192 * 4);
    float* Wm1T = (float*)alloc(4096 * 4);
    float* h1   = (float*)alloc((size_t)N * 128 * 4);
    float* x2   = (float*)alloc((size_t)N * 128 * 4);
    float* h2   = (float*)alloc((size_t)N * 64 * 4);
    float* hf   = (float*)alloc((size_t)N * 64 * 4);
    int*   rowp = (int*)alloc((size_t)(N + 1) * 4);
    int*   btot = (int*)alloc(64 * 4);
    int*   csrs = (int*)alloc((size_t)Etot * 4);
    // ---- contiguous zero-block (single memset) ----
    char* z0 = w;
    int*   deg  = (int*)alloc((size_t)N * 4);
    int*   curs = (int*)alloc((size_t)N * 4);
    float* as1  = (float*)alloc((size_t)N * 4 * 4);
    float* ad1  = (float*)alloc((size_t)N * 4 * 4);
    float* as2  = (float*)alloc((size_t)N * 4);
    float* ad2  = (float*)alloc((size_t)N * 4);
    char* z1 = w;
    float* uv = h1;   // h1 dead after edge1; reuse for u/v [N][64]

    (void)hipMemsetAsync(z0, 0, (size_t)(z1 - z0), stream);

    prep_kernel<<<112, 256, 0, stream>>>(W1, W2, Wm1, W1T, W2T, Wm1T);

    int EN = E + N;
    hist_kernel<<<(EN + 255) / 256, 256, 0, stream>>>(ei + E, E, N, deg);
    int nb = (N + 1023) / 1024;
    scan1_kernel<<<nb, 1024, 0, stream>>>(deg, rowp, btot, N);
    scan2_kernel<<<1, 64, 0, stream>>>(btot, nb);
    scan3_kernel<<<nb, 1024, 0, stream>>>(rowp, btot, N);
    scatter_kernel<<<(EN + 255) / 256, 256, 0, stream>>>(ei, ei + E, E, N, rowp, curs, csrs);

    dim3 g1((N + 63) / 64, 2);
    gemm_att_kernel<<<g1, 256, 0, stream>>>(x, W1T, atS1, atD1, h1, as1, ad1,
                                            N, 128, 4, 5);
    edge1_kernel<<<(N + 3) / 4, 256, 0, stream>>>(csrs, rowp, h1, as1, ad1,
                                                  b1, x2, N);
    dim3 g2((N + 63) / 64, 1);
    gemm_att_kernel<<<g2, 256, 0, stream>>>(x2, W2T, atS2, atD2, h2, as2, ad2,
                                            N, 64, 1, 6);
    edge2_kernel<<<(N + 3) / 4, 256, 0, stream>>>(csrs, rowp, h2, as2, ad2,
                                                  b2, hf, N);

    node_mlp_kernel<<<1024, 256, 0, stream>>>(hf, Wm1T, uv, N);
    pair_mlp_kernel<<<(2 * P + 255) / 256, 256, 0, stream>>>(ep, ep + P, uv, bm1,
                                                             Wm2, bm2, out, P);
}

// Round 5
// 296.716 us; speedup vs baseline: 1.5811x; 1.0941x over previous
//
#include <hip/hip_runtime.h>
#include <hip/hip_bf16.h>
#include <hip/hip_fp16.h>

// ---------------------------------------------------------------------------
// GAT link predictor: 2x GATConv + pair MLP.
// R5: fp16 gather tables (h1, h2, uv stored as __half; all compute fp32).
//     Gather traffic per edge: 512B->256B (L1), 256B->128B (L2).
//     Attention scores stay fp32. One-pass gather aggregation, scalar-load
//     CSR, deep-unrolled 16-gather fast path, hierarchical scan,
//     factorized MLP, single fused memset.
// ---------------------------------------------------------------------------

#define LRELU_SLOPE 0.2f

__device__ inline unsigned pkhalf2(float a, float b) {
    __half2 h = __floats2half2_rn(a, b);
    return *(unsigned*)&h;
}

// ---- weight pre-transpose (so GEMM W reads are wave-uniform -> s_load) ----
__global__ void __launch_bounds__(256) prep_kernel(
    const float* __restrict__ W1, const float* __restrict__ W2,
    const float* __restrict__ Wm1,
    float* __restrict__ W1T, float* __restrict__ W2T, float* __restrict__ Wm1T)
{
    int i = blockIdx.x * 256 + threadIdx.x;
    if (i < 16384) {                       // W1 [128][128] -> W1T [128][128]
        int k = i >> 7, j = i & 127;
        W1T[j * 128 + k] = W1[i];
    } else if (i < 16384 + 8192) {         // W2 [128][64] -> W2T [64][128]
        int t = i - 16384;
        int k = t >> 6, j = t & 63;
        W2T[j * 128 + k] = W2[t];
    } else if (i < 16384 + 8192 + 4096) {  // Wm1 [128][32] -> Wm1T [32][128]
        int t = i - 24576;
        int k = t >> 5, j = t & 31;
        Wm1T[j * 128 + k] = Wm1[t];
    }
}

// ---- CSR build ----
__global__ void __launch_bounds__(256) hist_kernel(
    const int* __restrict__ dst, int E, int N, int* __restrict__ deg)
{
    int i = blockIdx.x * 256 + threadIdx.x;
    if (i >= E + N) return;
    int d = (i < E) ? dst[i] : (i - E);
    atomicAdd(deg + d, 1);
}

// hierarchical scan: per-1024-block inclusive scan + block totals
__global__ void __launch_bounds__(1024) scan1_kernel(
    const int* __restrict__ deg, int* __restrict__ rowp,
    int* __restrict__ btot, int n)
{
    __shared__ int wsum[16];
    int t = threadIdx.x, lane = t & 63, wid = t >> 6;
    int idx = blockIdx.x * 1024 + t;
    int v = (idx < n) ? deg[idx] : 0;
    #pragma unroll
    for (int off = 1; off < 64; off <<= 1) {
        int y = __shfl_up(v, off);
        if (lane >= off) v += y;
    }
    if (lane == 63) wsum[wid] = v;
    __syncthreads();
    if (wid == 0) {
        int s = (lane < 16) ? wsum[lane] : 0;
        #pragma unroll
        for (int off = 1; off < 16; off <<= 1) {
            int y = __shfl_up(s, off);
            if (lane >= off) s += y;
        }
        if (lane < 16) wsum[lane] = s;
    }
    __syncthreads();
    if (wid > 0) v += wsum[wid - 1];
    if (idx < n) rowp[idx + 1] = v;
    if (t == 1023) btot[blockIdx.x] = v;
    if (idx == 0) rowp[0] = 0;
}

__global__ void __launch_bounds__(64) scan2_kernel(int* __restrict__ btot, int nb)
{
    int lane = threadIdx.x;
    int v = (lane < nb) ? btot[lane] : 0;
    #pragma unroll
    for (int off = 1; off < 64; off <<= 1) {
        int y = __shfl_up(v, off);
        if (lane >= off) v += y;
    }
    if (lane < nb) btot[lane] = v;
}

__global__ void __launch_bounds__(1024) scan3_kernel(
    int* __restrict__ rowp, const int* __restrict__ btot, int n)
{
    if (blockIdx.x == 0) return;
    int idx = blockIdx.x * 1024 + threadIdx.x;
    if (idx < n) rowp[idx + 1] += btot[blockIdx.x - 1];
}

__global__ void __launch_bounds__(256) scatter_kernel(
    const int* __restrict__ src, const int* __restrict__ dst, int E, int N,
    const int* __restrict__ rowptr, int* __restrict__ cursor,
    int* __restrict__ csrs)
{
    int i = blockIdx.x * 256 + threadIdx.x;
    if (i >= E + N) return;
    int s, d;
    if (i < E) { s = src[i]; d = dst[i]; } else { s = d = i - E; }
    int pos = rowptr[d] + atomicAdd(cursor + d, 1);
    csrs[pos] = s;
}

// ---- fused GEMM + attention-score epilogue; OUT stored fp16 ----
// Block: 256 threads = 4 waves; 64 rows x 64 cols. lane = row, wave = 16-col
// slice. x tile in LDS (stride 132), W reads wave-uniform -> s_load.
__global__ void __launch_bounds__(256) gemm_att_kernel(
    const float* __restrict__ X, const float* __restrict__ WT,
    const float* __restrict__ atts, const float* __restrict__ attd,
    __half* __restrict__ OUT, float* __restrict__ oas, float* __restrict__ oad,
    int N, int ncols, int H, int headShift)
{
    __shared__ float xs[64 * 132];
    int tid = threadIdx.x;
    int rowBase = blockIdx.x * 64;
    int colBase = blockIdx.y * 64;
    for (int i = tid; i < 64 * 32; i += 256) {
        int r = i >> 5, k4 = i & 31;
        int gr = rowBase + r;
        float4 v = (gr < N) ? ((const float4*)(X + (size_t)gr * 128))[k4]
                            : make_float4(0.f, 0.f, 0.f, 0.f);
        *(float4*)(xs + r * 132 + k4 * 4) = v;
    }
    __syncthreads();
    int lane = tid & 63;
    int wv = __builtin_amdgcn_readfirstlane(tid >> 6);
    int jb = colBase + wv * 16;
    const float* wbase = WT + (size_t)jb * 128;
    float acc[16];
    #pragma unroll
    for (int i = 0; i < 16; i++) acc[i] = 0.f;
    const float* xr = xs + lane * 132;
    for (int k0 = 0; k0 < 128; k0 += 4) {
        float4 xv = *(const float4*)(xr + k0);
        #pragma unroll
        for (int i = 0; i < 16; i++) {
            const float* wr = wbase + i * 128 + k0;   // uniform -> s_load
            acc[i] = fmaf(xv.x, wr[0], acc[i]);
            acc[i] = fmaf(xv.y, wr[1], acc[i]);
            acc[i] = fmaf(xv.z, wr[2], acc[i]);
            acc[i] = fmaf(xv.w, wr[3], acc[i]);
        }
    }
    int row = rowBase + lane;
    if (row < N) {
        float pas = 0.f, pad_ = 0.f;
        #pragma unroll
        for (int i = 0; i < 16; i++) {
            pas  = fmaf(acc[i], atts[jb + i], pas);
            pad_ = fmaf(acc[i], attd[jb + i], pad_);
        }
        int head = jb >> headShift;
        atomicAdd(oas + (size_t)row * H + head, pas);
        atomicAdd(oad + (size_t)row * H + head, pad_);
        // pack 16 fp32 -> 16 fp16 (32 B, two dwordx4 stores)
        uint4 w0, w1;
        w0.x = pkhalf2(acc[0],  acc[1]);  w0.y = pkhalf2(acc[2],  acc[3]);
        w0.z = pkhalf2(acc[4],  acc[5]);  w0.w = pkhalf2(acc[6],  acc[7]);
        w1.x = pkhalf2(acc[8],  acc[9]);  w1.y = pkhalf2(acc[10], acc[11]);
        w1.z = pkhalf2(acc[12], acc[13]); w1.w = pkhalf2(acc[14], acc[15]);
        __half* op = OUT + (size_t)row * ncols + jb;
        *(uint4*)(op)     = w0;
        *(uint4*)(op + 8) = w1;
    }
}

// ---- layer-1 edge pass: one wave per node; 16-edge chunks.
// Weights: lane=(el<<2)|hh. Gather: s via uniform s_load, 16 independent
// half2 gathers in flight in the cnt==16 fast path; lane owns channels
// {2lane, 2lane+1}.
__global__ void __launch_bounds__(256) edge1_kernel(
    const int* __restrict__ csr, const int* __restrict__ rowp,
    const __half2* __restrict__ h1, const float* __restrict__ as1,
    const float* __restrict__ ad1, const float* __restrict__ b1,
    float* __restrict__ x2, int N)
{
    int lane = threadIdx.x & 63;
    int n = __builtin_amdgcn_readfirstlane(blockIdx.x * 4 + (threadIdx.x >> 6));
    if (n >= N) return;
    int rs = rowp[n], re = rowp[n + 1];
    int hd = lane >> 4;
    int el = lane >> 2, hh = lane & 3;
    float adv = ad1[n * 4 + hh];
    float accx = 0.f, accy = 0.f, srun = 0.f;
    for (int base = rs; base < re; base += 16) {
        int cnt = re - base; if (cnt > 16) cnt = 16;
        float wv = 0.f;
        if (el < cnt) {
            int s = csr[base + el];
            float e = as1[s * 4 + hh] + adv;
            e = e > 0.f ? e : LRELU_SLOPE * e;
            wv = __expf(e);
        }
        float t = wv;
        t += __shfl_xor(t, 4);  t += __shfl_xor(t, 8);
        t += __shfl_xor(t, 16); t += __shfl_xor(t, 32);
        srun += t;
        if (cnt == 16) {
            #pragma unroll
            for (int e2 = 0; e2 < 16; ++e2) {
                int s = csr[base + e2];                    // uniform -> s_load
                float av = __shfl(wv, (e2 << 2) | hd);
                float2 v = __half22float2(h1[(size_t)s * 64 + lane]);
                accx = fmaf(av, v.x, accx);
                accy = fmaf(av, v.y, accy);
            }
        } else {
            for (int e2 = 0; e2 < cnt; ++e2) {
                int s = csr[base + e2];
                float av = __shfl(wv, (e2 << 2) | hd);
                float2 v = __half22float2(h1[(size_t)s * 64 + lane]);
                accx = fmaf(av, v.x, accx);
                accy = fmaf(av, v.y, accy);
            }
        }
    }
    float sden = __shfl(srun, hd) + 1e-16f;
    float inv = 1.f / sden;
    float2 bv = *(const float2*)(b1 + lane * 2);
    float o0 = accx * inv + bv.x;
    float o1 = accy * inv + bv.y;
    o0 = o0 > 0.f ? o0 : (__expf(o0) - 1.f);   // ELU
    o1 = o1 > 0.f ? o1 : (__expf(o1) - 1.f);
    *(float2*)(x2 + (size_t)n * 128 + lane * 2) = make_float2(o0, o1);
}

// ---- layer-2 edge pass (1 head, 64 channels; lane = channel) ----
__global__ void __launch_bounds__(256) edge2_kernel(
    const int* __restrict__ csr, const int* __restrict__ rowp,
    const __half* __restrict__ h2, const float* __restrict__ as2,
    const float* __restrict__ ad2, const float* __restrict__ b2,
    float* __restrict__ hf, int N)
{
    int lane = threadIdx.x & 63;
    int n = __builtin_amdgcn_readfirstlane(blockIdx.x * 4 + (threadIdx.x >> 6));
    if (n >= N) return;
    int rs = rowp[n], re = rowp[n + 1];
    float adv = ad2[n];
    float acc = 0.f, srun = 0.f;
    for (int base = rs; base < re; base += 16) {
        int cnt = re - base; if (cnt > 16) cnt = 16;
        float wv = 0.f;
        if (lane < cnt) {
            int s = csr[base + lane];
            float e = as2[s] + adv;
            e = e > 0.f ? e : LRELU_SLOPE * e;
            wv = __expf(e);
        }
        srun += wv;
        if (cnt == 16) {
            #pragma unroll
            for (int e2 = 0; e2 < 16; ++e2) {
                int s = csr[base + e2];                    // uniform -> s_load
                float av = __shfl(wv, e2);
                acc = fmaf(av, __half2float(h2[(size_t)s * 64 + lane]), acc);
            }
        } else {
            for (int e2 = 0; e2 < cnt; ++e2) {
                int s = csr[base + e2];
                float av = __shfl(wv, e2);
                acc = fmaf(av, __half2float(h2[(size_t)s * 64 + lane]), acc);
            }
        }
    }
    #pragma unroll
    for (int m = 1; m < 64; m <<= 1) srun += __shfl_xor(srun, m);
    float o = acc / (srun + 1e-16f) + b2[lane];
    hf[(size_t)n * 64 + lane] = o;
}

// ---- per-node MLP projections: u[n] = hf[n]@Wm1_top, v[n] = hf[n]@Wm1_bot --
// Output uv stored fp16 (gathered randomly by pair_mlp).
__global__ void __launch_bounds__(256) node_mlp_kernel(
    const float* __restrict__ hf, const float* __restrict__ Wm1T,
    __half* __restrict__ uv, int N)
{
    int lane = threadIdx.x & 63;
    int j = lane & 31, half = lane >> 5;
    const float* wr = Wm1T + j * 128 + half * 64;   // Wm1T[j][half*64 + k]
    float wreg[64];
    #pragma unroll
    for (int q = 0; q < 16; q++) {
        float4 t = ((const float4*)wr)[q];
        wreg[q*4] = t.x; wreg[q*4+1] = t.y; wreg[q*4+2] = t.z; wreg[q*4+3] = t.w;
    }
    int wgid = __builtin_amdgcn_readfirstlane(blockIdx.x * 4 + (threadIdx.x >> 6));
    int nwaves = gridDim.x * 4;
    for (int n = wgid; n < N; n += nwaves) {
        const float* hr = hf + (size_t)n * 64;
        float acc = 0.f;
        #pragma unroll
        for (int k = 0; k < 64; k += 4) {
            float4 hv = *(const float4*)(hr + k);   // uniform across wave
            acc = fmaf(hv.x, wreg[k],   acc);
            acc = fmaf(hv.y, wreg[k+1], acc);
            acc = fmaf(hv.z, wreg[k+2], acc);
            acc = fmaf(hv.w, wreg[k+3], acc);
        }
        uv[(size_t)n * 64 + lane] = __float2half_rn(acc);
    }
}

// ---- pair MLP: 2 lanes per pair (16 hidden units each), shfl-reduce ----
__global__ void __launch_bounds__(256) pair_mlp_kernel(
    const int* __restrict__ ps, const int* __restrict__ pd,
    const __half2* __restrict__ uv, const float* __restrict__ bm1,
    const float* __restrict__ Wm2, const float* __restrict__ bm2,
    float* __restrict__ out, int P)
{
    int gid = blockIdx.x * 256 + threadIdx.x;
    int p = gid >> 1;
    if (p >= P) return;
    int half = gid & 1;
    int j0 = half * 8;                                  // half2 offset (16 ch)
    int a = ps[p], b = pd[p];
    const __half2* ua = uv + (size_t)a * 32 + j0;       // u[a][16 ch]
    const __half2* vb = uv + (size_t)b * 32 + 16 + j0;  // v[b][16 ch]
    float r = 0.f;
    #pragma unroll
    for (int q = 0; q < 8; q++) {
        float2 uu = __half22float2(ua[q]);
        float2 vv = __half22float2(vb[q]);
        float2 bb = *(const float2*)(bm1 + half * 16 + q * 2);
        float2 ww = *(const float2*)(Wm2 + half * 16 + q * 2);
        float h0 = uu.x + vv.x + bb.x; h0 = h0 > 0.f ? h0 : 0.f; r = fmaf(h0, ww.x, r);
        float h1 = uu.y + vv.y + bb.y; h1 = h1 > 0.f ? h1 : 0.f; r = fmaf(h1, ww.y, r);
    }
    r += __shfl_xor(r, 1);
    if (half == 0) out[p] = r + bm2[0];
}

extern "C" void kernel_launch(void* const* d_in, const int* in_sizes, int n_in,
                              void* d_out, int out_size, void* d_ws, size_t ws_size,
                              hipStream_t stream)
{
    const float* x    = (const float*)d_in[0];
    const int*   ei   = (const int*)  d_in[1];
    const int*   ep   = (const int*)  d_in[2];
    const float* W1   = (const float*)d_in[3];
    const float* atS1 = (const float*)d_in[4];
    const float* atD1 = (const float*)d_in[5];
    const float* b1   = (const float*)d_in[6];
    const float* W2   = (const float*)d_in[7];
    const float* atS2 = (const float*)d_in[8];
    const float* atD2 = (const float*)d_in[9];
    const float* b2   = (const float*)d_in[10];
    const float* Wm1  = (const float*)d_in[11];
    const float* bm1  = (const float*)d_in[12];
    const float* Wm2  = (const float*)d_in[13];
    const float* bm2  = (const float*)d_in[14];
    float* out = (float*)d_out;

    int N = in_sizes[0] / 128;
    int E = in_sizes[1] / 2;
    int P = in_sizes[2] / 2;
    int Etot = E + N;

    // workspace carve (256B aligned)
    char* w = (char*)d_ws;
    auto alloc = [&](size_t bytes) {
        char* p = w; w += (bytes + 255) & ~(size_t)255; return p;
    };
    float*  W1T  = (float*)alloc(16384 * 4);
    float*  W2T  = (float*)alloc(8192 * 4);
    float*  Wm1T = (float*)alloc(4096 * 4);
    __half* h1   = (__half*)alloc((size_t)N * 128 * 2);  // fp16 gather table
    float*  x2   = (float*)alloc((size_t)N * 128 * 4);
    __half* h2   = (__half*)alloc((size_t)N * 64 * 2);   // fp16 gather table
    float*  hf   = (float*)alloc((size_t)N * 64 * 4);
    int*    rowp = (int*)alloc((size_t)(N + 1) * 4);
    int*    btot = (int*)alloc(64 * 4);
    int*    csrs = (int*)alloc((size_t)Etot * 4);
    // ---- contiguous zero-block (single memset) ----
    char* z0 = w;
    int*   deg  = (int*)alloc((size_t)N * 4);
    int*   curs = (int*)alloc((size_t)N * 4);
    float* as1  = (float*)alloc((size_t)N * 4 * 4);
    float* ad1  = (float*)alloc((size_t)N * 4 * 4);
    float* as2  = (float*)alloc((size_t)N * 4);
    float* ad2  = (float*)alloc((size_t)N * 4);
    char* z1 = w;
    __half* uv = (__half*)alloc((size_t)N * 64 * 2);     // fp16 gather table

    (void)hipMemsetAsync(z0, 0, (size_t)(z1 - z0), stream);

    prep_kernel<<<112, 256, 0, stream>>>(W1, W2, Wm1, W1T, W2T, Wm1T);

    int EN = E + N;
    hist_kernel<<<(EN + 255) / 256, 256, 0, stream>>>(ei + E, E, N, deg);
    int nb = (N + 1023) / 1024;
    scan1_kernel<<<nb, 1024, 0, stream>>>(deg, rowp, btot, N);
    scan2_kernel<<<1, 64, 0, stream>>>(btot, nb);
    scan3_kernel<<<nb, 1024, 0, stream>>>(rowp, btot, N);
    scatter_kernel<<<(EN + 255) / 256, 256, 0, stream>>>(ei, ei + E, E, N, rowp, curs, csrs);

    dim3 g1((N + 63) / 64, 2);
    gemm_att_kernel<<<g1, 256, 0, stream>>>(x, W1T, atS1, atD1, h1, as1, ad1,
                                            N, 128, 4, 5);
    edge1_kernel<<<(N + 3) / 4, 256, 0, stream>>>(csrs, rowp, (const __half2*)h1,
                                                  as1, ad1, b1, x2, N);
    dim3 g2((N + 63) / 64, 1);
    gemm_att_kernel<<<g2, 256, 0, stream>>>(x2, W2T, atS2, atD2, h2, as2, ad2,
                                            N, 64, 1, 6);
    edge2_kernel<<<(N + 3) / 4, 256, 0, stream>>>(csrs, rowp, h2, as2, ad2,
                                                  b2, hf, N);

    node_mlp_kernel<<<1024, 256, 0, stream>>>(hf, Wm1T, uv, N);
    pair_mlp_kernel<<<(2 * P + 255) / 256, 256, 0, stream>>>(ep, ep + P,
                                                             (const __half2*)uv,
                                                             bm1, Wm2, bm2, out, P);
}